// Round 1
// baseline (208.312 us; speedup 1.0000x reference)
//
#include <hip/hip_runtime.h>

constexpr int Bn = 128, Vn = 256, Fn = 64;
constexpr int NSLR = 68, NSn = 4, NLRn = 64;
constexpr int Kn = 40, NOUTn = 128;
constexpr int ROWS = Bn * Vn; // 32768

__device__ __forceinline__ int mbcnt64(unsigned long long m) {
  return __builtin_amdgcn_mbcnt_hi((unsigned)(m >> 32),
         __builtin_amdgcn_mbcnt_lo((unsigned)(m & 0xFFFFFFFFull), 0));
}

// ---------------- K0: xmean[b][f] = mean over V ----------------
__global__ __launch_bounds__(256) void kmean(const float* __restrict__ x,
                                             float* __restrict__ xmean) {
  const int b = blockIdx.x;
  const int f = threadIdx.x & 63;
  const int vg = threadIdx.x >> 6;
  const float* xb = x + (size_t)b * Vn * Fn;
  float p = 0.f;
  for (int s = 0; s < 64; ++s) p += xb[(vg * 64 + s) * Fn + f];
  __shared__ float ps[4][64];
  ps[vg][f] = p;
  __syncthreads();
  if (threadIdx.x < 64) {
    float m = ((ps[0][f] + ps[1][f]) + (ps[2][f] + ps[3][f])) * (1.f / 256.f);
    xmean[b * 64 + f] = m;
  }
}

// ---------------- unified tiled fp32 GEMM over concat-gathered A ----------------
// A[row][k] = k<64: x[row][k] ; k<128: xmean[b][k-64] ; k<192: ftm[row][k-128] ; else ftx
// tile: 128 rows x 128 cols, 8x8 per thread, K chunked by 64.
template <int KTOT, bool IS_OUT>
__global__ __launch_bounds__(256) void kgemm(
    const float* __restrict__ x, const float* __restrict__ xmean,
    const float* __restrict__ ftm, const float* __restrict__ ftx,
    const float* __restrict__ W, const float* __restrict__ bias,
    float* __restrict__ s_ws, float* __restrict__ lr_ws, float* __restrict__ outp) {
  constexpr int NW = IS_OUT ? NOUTn : NSLR;  // real W row length
  __shared__ float At[64 * 128];  // [k][r] transposed A tile
  __shared__ float Ws[64 * 128];  // [k][c]
  const int t = threadIdx.x;
  const int rg = t & 15;   // rows rg*8 .. rg*8+7
  const int g = t >> 4;    // cols g*8 .. g*8+7
  const int rowBase = blockIdx.x * 128;

  float acc[8][8];
#pragma unroll
  for (int a = 0; a < 8; ++a)
#pragma unroll
    for (int c = 0; c < 8; ++c) acc[a][c] = 0.f;

  const int r_st = t >> 1;  // staging row 0..127
  const int h_st = t & 1;   // staging k-half
  const int row_st = rowBase + r_st;
  const int b_st = row_st >> 8;

#pragma unroll
  for (int kc = 0; kc < KTOT; kc += 64) {
    __syncthreads();
    // ---- stage A^T ----
    {
      const float* src;
      if (kc == 0)        src = x + (size_t)row_st * Fn;
      else if (kc == 64)  src = xmean + b_st * Fn;
      else if (kc == 128) src = ftm + (size_t)row_st * NLRn;
      else                src = ftx + (size_t)row_st * NLRn;
#pragma unroll
      for (int i = 0; i < 8; ++i) {
        int k = h_st * 32 + i * 4;
        float4 v4 = *(const float4*)(src + k);
        At[(k + 0) * 128 + r_st] = v4.x;
        At[(k + 1) * 128 + r_st] = v4.y;
        At[(k + 2) * 128 + r_st] = v4.z;
        At[(k + 3) * 128 + r_st] = v4.w;
      }
    }
    // ---- stage W chunk [64][128], zero-padded cols ----
#pragma unroll
    for (int u = 0; u < 32; ++u) {
      int pos = t + u * 256;
      int k = pos >> 7, c = pos & 127;
      float w = (c < NW) ? W[(size_t)(kc + k) * NW + c] : 0.f;
      Ws[k * 128 + c] = w;
    }
    __syncthreads();
    // ---- compute ----
    for (int k = 0; k < 64; ++k) {
      float4 a0 = *(const float4*)&At[k * 128 + rg * 8];
      float4 a1 = *(const float4*)&At[k * 128 + rg * 8 + 4];
      float4 b0 = *(const float4*)&Ws[k * 128 + g * 8];
      float4 b1 = *(const float4*)&Ws[k * 128 + g * 8 + 4];
      float ar[8] = {a0.x, a0.y, a0.z, a0.w, a1.x, a1.y, a1.z, a1.w};
      float bc[8] = {b0.x, b0.y, b0.z, b0.w, b1.x, b1.y, b1.z, b1.w};
#pragma unroll
      for (int rr = 0; rr < 8; ++rr)
#pragma unroll
        for (int cc = 0; cc < 8; ++cc)
          acc[rr][cc] = fmaf(ar[rr], bc[cc], acc[rr][cc]);
    }
  }
  // ---- epilogue ----
  if (IS_OUT) {
    float4 bb0 = *(const float4*)&bias[g * 8];
    float4 bb1 = *(const float4*)&bias[g * 8 + 4];
    float bb[8] = {bb0.x, bb0.y, bb0.z, bb0.w, bb1.x, bb1.y, bb1.z, bb1.w};
#pragma unroll
    for (int rr = 0; rr < 8; ++rr) {
      int row = rowBase + rg * 8 + rr;
      float o[8];
#pragma unroll
      for (int cc = 0; cc < 8; ++cc) {
        float vv = acc[rr][cc] + bb[cc];
        o[cc] = vv > 0.f ? vv : 0.f;
      }
      float4* dst = (float4*)&outp[(size_t)row * NOUTn + g * 8];
      dst[0] = make_float4(o[0], o[1], o[2], o[3]);
      dst[1] = make_float4(o[4], o[5], o[6], o[7]);
    }
  } else {
#pragma unroll
    for (int cc = 0; cc < 8; ++cc) {
      int c = g * 8 + cc;
      if (c < NSLR) {
        float bia = bias[c];
#pragma unroll
        for (int rr = 0; rr < 8; ++rr) {
          int row = rowBase + rg * 8 + rr;
          float vv = acc[rr][cc] + bia;
          vv = vv > 0.f ? vv : 0.f;
          int bb_ = row >> 8, v_ = row & 255;
          if (c < NSn) s_ws[bb_ * 1024 + c * 256 + v_] = vv;      // [b][c][v]
          else         lr_ws[(size_t)row * NLRn + (c - NSn)] = vv; // [row][f]
        }
      }
    }
  }
}

// ---------------- K3: per-row KNN select + weighted mean/max ----------------
// wave per row. 256 d2 keys spread 4-per-lane; exact Kth-smallest via ballot
// binary search; stable tie-break by index (matches jax.lax.top_k).
__global__ __launch_bounds__(256) void kselect(const float* __restrict__ s_ws,
                                               const float* __restrict__ lr_ws,
                                               float* __restrict__ ftm,
                                               float* __restrict__ ftx) {
  __shared__ float sT[4 * 256];      // [c][v]
  __shared__ float lrs[256 * 64];    // [v][f]
  __shared__ unsigned int lst[4][Kn];
  const int t = threadIdx.x;
  const int lane = t & 63;
  const int w = t >> 6;
  const int b = blockIdx.x >> 2;
  const int quarter = blockIdx.x & 3;

  for (int u = t; u < 1024; u += 256) sT[u] = s_ws[b * 1024 + u];
  {
    const float4* src = (const float4*)(lr_ws + (size_t)b * (Vn * NLRn));
    float4* dst = (float4*)lrs;
    for (int u = t; u < (Vn * NLRn / 4); u += 256) dst[u] = src[u];
  }
  __syncthreads();

  const float C = -14.4269504088896340736f;  // -10 * log2(e)

  for (int it = 0; it < 16; ++it) {
    const int i = quarter * 64 + w * 16 + it;
    const float si0 = sT[0 * 256 + i], si1 = sT[1 * 256 + i];
    const float si2 = sT[2 * 256 + i], si3 = sT[3 * 256 + i];
    unsigned int kb[4];
    float vv[4];
#pragma unroll
    for (int q = 0; q < 4; ++q) {
      int j = q * 64 + lane;
      float d0 = sT[0 * 256 + j] - si0;
      float d1 = sT[1 * 256 + j] - si1;
      float d2_ = sT[2 * 256 + j] - si2;
      float d3 = sT[3 * 256 + j] - si3;
      float dd = ((d0 * d0 + d1 * d1) + d2_ * d2_) + d3 * d3;
      kb[q] = __float_as_uint(dd);     // d2>=0 -> bits are order-preserving
      vv[q] = exp2f(C * dd);
    }
    // greedy bitwise search: T* = Kth smallest key (max T with cnt(<T) < K)
    unsigned int T = 0;
    for (int bit = 30; bit >= 0; --bit) {
      unsigned int cand = T | (1u << bit);
      int cnt = __popcll(__ballot(kb[0] < cand)) + __popcll(__ballot(kb[1] < cand)) +
                __popcll(__ballot(kb[2] < cand)) + __popcll(__ballot(kb[3] < cand));
      if (cnt < Kn) T = cand;
    }
    int nlt = __popcll(__ballot(kb[0] < T)) + __popcll(__ballot(kb[1] < T)) +
              __popcll(__ballot(kb[2] < T)) + __popcll(__ballot(kb[3] < T));
    int rem = Kn - nlt;  // how many ==T to take, in ascending-j order
    int base = 0, ecum = 0;
#pragma unroll
    for (int q = 0; q < 4; ++q) {
      bool lt = kb[q] < T;
      bool eq = kb[q] == T;
      unsigned long long meq = __ballot(eq);
      int eqrank = ecum + mbcnt64(meq);
      bool sel = lt || (eq && (eqrank < rem));
      unsigned long long msel = __ballot(sel);
      int pos = base + mbcnt64(msel);
      if (sel)
        lst[w][pos] = (__float_as_uint(vv[q]) & 0xFFFFFF00u) | (unsigned)(q * 64 + lane);
      base += __popcll(msel);
      ecum += __popcll(meq);
    }
    // feature-parallel accumulate: lane = feature
    float accm = 0.f, accx = 0.f;  // ft >= 0 so 0-init max is exact
#pragma unroll 8
    for (int tt = 0; tt < Kn; ++tt) {
      unsigned int p = lst[w][tt];
      int j = p & 0xFF;
      float v = __uint_as_float(p & 0xFFFFFF00u);
      float tv = v * lrs[j * 64 + lane];
      accm += tv;
      accx = fmaxf(accx, tv);
    }
    size_t ro = ((size_t)(b * 256 + i)) * 64 + lane;
    ftm[ro] = accm * (1.f / 40.f);
    ftx[ro] = accx;
  }
}

extern "C" void kernel_launch(void* const* d_in, const int* in_sizes, int n_in,
                              void* d_out, int out_size, void* d_ws, size_t ws_size,
                              hipStream_t stream) {
  const float* x = (const float*)d_in[0];
  const float* W_slr = (const float*)d_in[1];
  const float* b_slr = (const float*)d_in[2];
  const float* W_out = (const float*)d_in[3];
  const float* b_out = (const float*)d_in[4];
  float* out = (float*)d_out;

  float* ws = (float*)d_ws;
  float* xmean = ws;                       // 8192
  float* s_ws = xmean + 8192;              // 131072  [b][c][v]
  float* lr_ws = s_ws + 131072;            // 32768*64
  float* ftm = lr_ws + (size_t)ROWS * 64;  // 32768*64
  float* ftx = ftm + (size_t)ROWS * 64;    // 32768*64

  kmean<<<Bn, 256, 0, stream>>>(x, xmean);
  kgemm<128, false><<<ROWS / 128, 256, 0, stream>>>(x, xmean, nullptr, nullptr,
                                                    W_slr, b_slr, s_ws, lr_ws, nullptr);
  kselect<<<Bn * 4, 256, 0, stream>>>(s_ws, lr_ws, ftm, ftx);
  kgemm<256, true><<<ROWS / 128, 256, 0, stream>>>(x, xmean, ftm, ftx,
                                                   W_out, b_out, nullptr, nullptr, out);
}

// Round 2
// 174.405 us; speedup vs baseline: 1.1944x; 1.1944x over previous
//
#include <hip/hip_runtime.h>

constexpr int Bn = 128, Vn = 256, Fn = 64;
constexpr int NSLR = 68, NSn = 4, NLRn = 64;
constexpr int Kn = 40, NOUTn = 128;
constexpr int ROWS = Bn * Vn;  // 32768
constexpr int SLRS = 80;       // padded row stride of slr_ws: lr[0..63], s[64..67], pad

__device__ __forceinline__ int mbcnt64(unsigned long long m) {
  return __builtin_amdgcn_mbcnt_hi((unsigned)(m >> 32),
         __builtin_amdgcn_mbcnt_lo((unsigned)(m & 0xFFFFFFFFull), 0));
}

// ---------------- K0: xmean[b][f] = mean over V ----------------
__global__ __launch_bounds__(256) void kmean(const float* __restrict__ x,
                                             float* __restrict__ xmean) {
  const int b = blockIdx.x;
  const int f = threadIdx.x & 63;
  const int vg = threadIdx.x >> 6;
  const float* xb = x + (size_t)b * Vn * Fn;
  float p = 0.f;
  for (int s = 0; s < 64; ++s) p += xb[(vg * 64 + s) * Fn + f];
  __shared__ float ps[4][64];
  ps[vg][f] = p;
  __syncthreads();
  if (threadIdx.x < 64) {
    float m = ((ps[0][f] + ps[1][f]) + (ps[2][f] + ps[3][f])) * (1.f / 256.f);
    xmean[b * 64 + f] = m;
  }
}

// ---------------- tiled fp32 GEMM, 64 rows x 128 cols, 4x8 per thread ----------------
// A[row][k] chunks (64 each): 0:x  1:xmean  2:ftm  3:ftx
template <int NCH, bool IS_OUT>
__global__ __launch_bounds__(256) void kgemm(
    const float* __restrict__ x, const float* __restrict__ xmean,
    const float* __restrict__ ftm, const float* __restrict__ ftx,
    const float* __restrict__ W, const float* __restrict__ bias,
    float* __restrict__ slr_ws, float* __restrict__ outp) {
  constexpr int NW = IS_OUT ? NOUTn : NSLR;
  __shared__ float As[64 * 68];   // [r][k], k-pad to 68
  __shared__ float Ws[64 * 128];  // [k][c]
  const int t = threadIdx.x;
  const int ty = t >> 4;  // rows ty*4 .. +3
  const int tx = t & 15;  // cols tx*8 .. +7
  const int rowBase = blockIdx.x * 64;

  float acc[4][8];
#pragma unroll
  for (int a = 0; a < 4; ++a)
#pragma unroll
    for (int c = 0; c < 8; ++c) acc[a][c] = 0.f;

  const int r_st = t >> 2;          // staging row 0..63
  const int q_st = t & 3;           // k-quarter
  const int row_st = rowBase + r_st;
  const int b_st = row_st >> 8;

#pragma unroll
  for (int kc = 0; kc < NCH; ++kc) {
    __syncthreads();
    {
      const float* src = (kc == 0) ? x + (size_t)row_st * Fn
                       : (kc == 1) ? xmean + (size_t)b_st * Fn
                       : (kc == 2) ? ftm + (size_t)row_st * NLRn
                                   : ftx + (size_t)row_st * NLRn;
#pragma unroll
      for (int i = 0; i < 4; ++i) {
        int k0 = q_st * 16 + i * 4;
        float4 v = *(const float4*)(src + k0);
        *(float4*)&As[r_st * 68 + k0] = v;
      }
    }
#pragma unroll
    for (int u = 0; u < 32; ++u) {
      int pos = t + u * 256;
      int k = pos >> 7, c = pos & 127;
      Ws[k * 128 + c] = (c < NW) ? W[(size_t)(kc * 64 + k) * NW + c] : 0.f;
    }
    __syncthreads();
    for (int k = 0; k < 64; ++k) {
      float a[4];
#pragma unroll
      for (int rr = 0; rr < 4; ++rr) a[rr] = As[(ty * 4 + rr) * 68 + k];
      float4 b0 = *(const float4*)&Ws[k * 128 + tx * 8];
      float4 b1 = *(const float4*)&Ws[k * 128 + tx * 8 + 4];
      float bc[8] = {b0.x, b0.y, b0.z, b0.w, b1.x, b1.y, b1.z, b1.w};
#pragma unroll
      for (int rr = 0; rr < 4; ++rr)
#pragma unroll
        for (int cc = 0; cc < 8; ++cc)
          acc[rr][cc] = fmaf(a[rr], bc[cc], acc[rr][cc]);
    }
  }
  // ---- epilogue ----
  if (IS_OUT) {
    float4 bb0 = *(const float4*)&bias[tx * 8];
    float4 bb1 = *(const float4*)&bias[tx * 8 + 4];
    float bb[8] = {bb0.x, bb0.y, bb0.z, bb0.w, bb1.x, bb1.y, bb1.z, bb1.w};
#pragma unroll
    for (int rr = 0; rr < 4; ++rr) {
      int row = rowBase + ty * 4 + rr;
      float o[8];
#pragma unroll
      for (int cc = 0; cc < 8; ++cc) {
        float vv = acc[rr][cc] + bb[cc];
        o[cc] = vv > 0.f ? vv : 0.f;
      }
      float4* dst = (float4*)&outp[(size_t)row * NOUTn + tx * 8];
      dst[0] = make_float4(o[0], o[1], o[2], o[3]);
      dst[1] = make_float4(o[4], o[5], o[6], o[7]);
    }
  } else if (tx < 9) {
    float bb[8];
#pragma unroll
    for (int cc = 0; cc < 8; ++cc) {
      int c = tx * 8 + cc;
      bb[cc] = (c < NSLR) ? bias[c] : 0.f;
    }
#pragma unroll
    for (int rr = 0; rr < 4; ++rr) {
      int row = rowBase + ty * 4 + rr;
      float* dst = slr_ws + (size_t)row * SLRS;
      float o[8];
#pragma unroll
      for (int cc = 0; cc < 8; ++cc) {
        float vv = acc[rr][cc] + bb[cc];
        o[cc] = vv > 0.f ? vv : 0.f;
      }
      // col mapping: gemm col c<4 -> s at 64+c ; else lr at c-4
      float4 lo = make_float4(o[0], o[1], o[2], o[3]);
      float4 hi = make_float4(o[4], o[5], o[6], o[7]);
      if (tx == 0) {
        *(float4*)(dst + 64) = lo;   // s cols 0..3
        *(float4*)(dst + 0) = hi;    // lr cols 0..3
      } else {
        *(float4*)(dst + tx * 8 - 4) = lo;
        if (tx < 8) *(float4*)(dst + tx * 8) = hi;  // tx==8 hi half is pad cols 68..71
      }
    }
  }
}

// ---------------- K3: per-row KNN select + weighted mean/max ----------------
// wave per row-group: 4 rows/wave, 16 rows/block, grid Bn*16.
// 256 d2 keys 4-per-lane; exact stable Kth-smallest via ballot binary search.
__global__ __launch_bounds__(256) void kselect(const float* __restrict__ slr,
                                               float* __restrict__ ftm,
                                               float* __restrict__ ftx) {
  __shared__ float sT[4][256];
  __shared__ unsigned int lst[4][Kn];
  const int t = threadIdx.x;
  const int lane = t & 63;
  const int w = t >> 6;
  const int b = blockIdx.x >> 4;
  const int seg = blockIdx.x & 15;

  {
    float4 sv = *(const float4*)(slr + (size_t)(b * 256 + t) * SLRS + 64);
    sT[0][t] = sv.x; sT[1][t] = sv.y; sT[2][t] = sv.z; sT[3][t] = sv.w;
  }
  __syncthreads();

  const float C = -14.4269504088896340736f;  // -10 * log2(e)
  const float* lrbase = slr + (size_t)b * 256 * SLRS + lane;

  for (int it = 0; it < 4; ++it) {
    const int i = seg * 16 + w * 4 + it;
    const float si0 = sT[0][i], si1 = sT[1][i];
    const float si2 = sT[2][i], si3 = sT[3][i];
    unsigned int kb[4];
    float vv[4];
#pragma unroll
    for (int q = 0; q < 4; ++q) {
      int j = q * 64 + lane;
      float d0 = sT[0][j] - si0;
      float d1 = sT[1][j] - si1;
      float d2_ = sT[2][j] - si2;
      float d3 = sT[3][j] - si3;
      float dd = ((d0 * d0 + d1 * d1) + d2_ * d2_) + d3 * d3;
      kb[q] = __float_as_uint(dd);  // d2 >= 0 -> bits order-preserving
      vv[q] = exp2f(C * dd);
    }
    // T* = Kth-smallest key: max T with count(< T) < K
    unsigned int T = 0;
    for (int bit = 30; bit >= 0; --bit) {
      unsigned int cand = T | (1u << bit);
      int cnt = __popcll(__ballot(kb[0] < cand)) + __popcll(__ballot(kb[1] < cand)) +
                __popcll(__ballot(kb[2] < cand)) + __popcll(__ballot(kb[3] < cand));
      if (cnt < Kn) T = cand;
    }
    int nlt = __popcll(__ballot(kb[0] < T)) + __popcll(__ballot(kb[1] < T)) +
              __popcll(__ballot(kb[2] < T)) + __popcll(__ballot(kb[3] < T));
    int rem = Kn - nlt;  // ties taken in ascending-j order (stable, matches top_k)
    int base = 0, ecum = 0;
#pragma unroll
    for (int q = 0; q < 4; ++q) {
      bool lt = kb[q] < T;
      bool eq = kb[q] == T;
      unsigned long long meq = __ballot(eq);
      int eqrank = ecum + mbcnt64(meq);
      bool sel = lt || (eq && (eqrank < rem));
      unsigned long long msel = __ballot(sel);
      int pos = base + mbcnt64(msel);
      if (sel)
        lst[w][pos] = (__float_as_uint(vv[q]) & 0xFFFFFF00u) | (unsigned)(q * 64 + lane);
      base += __popcll(msel);
      ecum += __popcll(meq);
    }
    // feature-parallel accumulate: lane = feature; lr gathered from global (L2-hot)
    float accm = 0.f, accx = 0.f;  // ft >= 0 so 0-init max is exact
#pragma unroll 8
    for (int tt = 0; tt < Kn; ++tt) {
      unsigned int p = lst[w][tt];
      int j = p & 0xFF;
      float v = __uint_as_float(p & 0xFFFFFF00u);
      float tv = v * lrbase[j * SLRS];
      accm += tv;
      accx = fmaxf(accx, tv);
    }
    size_t ro = ((size_t)(b * 256 + i)) * 64 + lane;
    ftm[ro] = accm * (1.f / 40.f);
    ftx[ro] = accx;
  }
}

extern "C" void kernel_launch(void* const* d_in, const int* in_sizes, int n_in,
                              void* d_out, int out_size, void* d_ws, size_t ws_size,
                              hipStream_t stream) {
  const float* x = (const float*)d_in[0];
  const float* W_slr = (const float*)d_in[1];
  const float* b_slr = (const float*)d_in[2];
  const float* W_out = (const float*)d_in[3];
  const float* b_out = (const float*)d_in[4];
  float* out = (float*)d_out;

  float* ws = (float*)d_ws;
  float* xmean = ws;                          // 8192
  float* slr_ws = xmean + 8192;               // ROWS*80
  float* ftm = slr_ws + (size_t)ROWS * SLRS;  // ROWS*64
  float* ftx = ftm + (size_t)ROWS * 64;       // ROWS*64

  kmean<<<Bn, 256, 0, stream>>>(x, xmean);
  kgemm<2, false><<<ROWS / 64, 256, 0, stream>>>(x, xmean, nullptr, nullptr,
                                                 W_slr, b_slr, slr_ws, nullptr);
  kselect<<<Bn * 16, 256, 0, stream>>>(slr_ws, ftm, ftx);
  kgemm<4, true><<<ROWS / 64, 256, 0, stream>>>(x, xmean, ftm, ftx,
                                                W_out, b_out, nullptr, out);
}

// Round 3
// 138.052 us; speedup vs baseline: 1.5089x; 1.2633x over previous
//
#include <hip/hip_runtime.h>

constexpr int Bn = 128, Vn = 256, Fn = 64;
constexpr int NSLR = 68, NSn = 4, NLRn = 64;
constexpr int Kn = 40, NOUTn = 128;
constexpr int ROWS = Bn * Vn;  // 32768

typedef __attribute__((ext_vector_type(8))) short short8;
typedef __attribute__((ext_vector_type(4))) float f32x4;

__device__ __forceinline__ int mbcnt64(unsigned long long m) {
  return __builtin_amdgcn_mbcnt_hi((unsigned)(m >> 32),
         __builtin_amdgcn_mbcnt_lo((unsigned)(m & 0xFFFFFFFFull), 0));
}

__device__ __forceinline__ unsigned short rneb(float v) {  // fp32 -> bf16 RNE
  unsigned u = __float_as_uint(v);
  unsigned r = u + 0x7FFFu + ((u >> 16) & 1u);
  return (unsigned short)(r >> 16);
}
__device__ __forceinline__ float bf2f(unsigned short h) {
  return __uint_as_float(((unsigned)h) << 16);
}

// ---------------- P0: transpose+split W -> [col][k] bf16 hi/lo ----------------
__global__ __launch_bounds__(256) void kprep_w(const float* __restrict__ W_slr,
                                               const float* __restrict__ W_out,
                                               short* __restrict__ wt1h, short* __restrict__ wt1l,
                                               short* __restrict__ wt2h, short* __restrict__ wt2l) {
  int id = blockIdx.x * 256 + threadIdx.x;
  if (id < 16384) {  // Wt1 [128 col][128 k], cols>=68 zero
    int col = id >> 7, k = id & 127;
    float val = (col < NSLR) ? W_slr[k * NSLR + col] : 0.f;
    unsigned short h = rneb(val);
    unsigned short lo = rneb(val - bf2f(h));
    wt1h[id] = (short)h; wt1l[id] = (short)lo;
  } else {           // Wt2 [128 col][256 k]
    int id2 = id - 16384;
    int col = id2 >> 8, k = id2 & 255;
    float val = W_out[k * NOUTn + col];
    unsigned short h = rneb(val);
    unsigned short lo = rneb(val - bf2f(h));
    wt2h[id2] = (short)h; wt2l[id2] = (short)lo;
  }
}

// ---------------- P1: split x -> bf16 hi/lo + mean over V (hi/lo) ----------------
__global__ __launch_bounds__(256) void kprep_x(const float* __restrict__ x,
                                               short* __restrict__ xhi, short* __restrict__ xlo,
                                               short* __restrict__ xmhi, short* __restrict__ xmlo) {
  const int b = blockIdx.x, t = threadIdx.x, f = t & 63, vg = t >> 6;
  const float* xb = x + (size_t)b * 16384;
  float sum = 0.f;
  for (int i = 0; i < 64; ++i) {
    int v = vg * 64 + i;
    float val = xb[v * 64 + f];
    sum += val;
    unsigned short h = rneb(val);
    unsigned short lo = rneb(val - bf2f(h));
    size_t o = (size_t)b * 16384 + v * 64 + f;
    xhi[o] = (short)h; xlo[o] = (short)lo;
  }
  __shared__ float ps[4][64];
  ps[vg][f] = sum;
  __syncthreads();
  if (t < 64) {
    float m = ((ps[0][f] + ps[1][f]) + (ps[2][f] + ps[3][f])) * (1.f / 256.f);
    unsigned short h = rneb(m);
    unsigned short lo = rneb(m - bf2f(h));
    xmhi[b * 64 + f] = (short)h; xmlo[b * 64 + f] = (short)lo;
  }
}

// ---------------- MFMA GEMM: 128x128 tile, 8 waves, 3-pass hi/lo bf16 ----------------
// A[row][k] chunks of 64: 0:x 1:xmean 2:ftm 3:ftx (all pre-split bf16 [row][64])
// B = Wt [col][KTOT] bf16 hi/lo. LDS [row][64] bf16 with XOR-16B swizzle.
template <int NCH, bool IS_OUT>
__global__ __launch_bounds__(512) void kgemm_mfma(
    const short* __restrict__ xhi, const short* __restrict__ xlo,
    const short* __restrict__ xmhi, const short* __restrict__ xmlo,
    const short* __restrict__ fmh, const short* __restrict__ fml,
    const short* __restrict__ fxh, const short* __restrict__ fxl,
    const short* __restrict__ wth, const short* __restrict__ wtl,
    const float* __restrict__ bias,
    float* __restrict__ s_ws, float* __restrict__ lr_ws,
    float* __restrict__ outp) {
  constexpr int KTOT = NCH * 64;
  __shared__ __align__(16) short Ah[8192], Al[8192], Bh[8192], Bl[8192];
  const int t = threadIdx.x;
  const int l = t & 63;
  const int w = t >> 6;
  const int wr = w >> 2, wc = w & 3;   // wave -> 64-row x 32-col sub-tile
  const int rowBase = blockIdx.x * 128;
  const int b = rowBase >> 8;

  f32x4 acc[4][2];
#pragma unroll
  for (int mf = 0; mf < 4; ++mf)
#pragma unroll
    for (int nf = 0; nf < 2; ++nf) acc[mf][nf] = (f32x4)(0.f);

  const int lr8 = l >> 3;            // dest row within seg
  const int ul = (l & 7) ^ lr8;      // logical 16B-unit to fetch (pre-swizzled src)

#pragma unroll
  for (int kc = 0; kc < NCH; ++kc) {
    __syncthreads();
#pragma unroll
    for (int rep = 0; rep < 2; ++rep) {
      const int s = w + rep * 8;       // segment 0..15 (8 rows each)
      const int arow = s * 8 + lr8;
      const short *gah, *gal;
      if (kc == 0)      { size_t o = (size_t)(rowBase + arow) * 64 + ul * 8; gah = xhi + o;  gal = xlo + o; }
      else if (kc == 1) { size_t o = (size_t)b * 64 + ul * 8;                gah = xmhi + o; gal = xmlo + o; }
      else if (kc == 2) { size_t o = (size_t)(rowBase + arow) * 64 + ul * 8; gah = fmh + o;  gal = fml + o; }
      else              { size_t o = (size_t)(rowBase + arow) * 64 + ul * 8; gah = fxh + o;  gal = fxl + o; }
      __builtin_amdgcn_global_load_lds((const __attribute__((address_space(1))) void*)gah,
                                       (__attribute__((address_space(3))) void*)&Ah[s * 512], 16, 0, 0);
      __builtin_amdgcn_global_load_lds((const __attribute__((address_space(1))) void*)gal,
                                       (__attribute__((address_space(3))) void*)&Al[s * 512], 16, 0, 0);
      const short* gbh = wth + (size_t)arow * KTOT + kc * 64 + ul * 8;
      const short* gbl = wtl + (size_t)arow * KTOT + kc * 64 + ul * 8;
      __builtin_amdgcn_global_load_lds((const __attribute__((address_space(1))) void*)gbh,
                                       (__attribute__((address_space(3))) void*)&Bh[s * 512], 16, 0, 0);
      __builtin_amdgcn_global_load_lds((const __attribute__((address_space(1))) void*)gbl,
                                       (__attribute__((address_space(3))) void*)&Bl[s * 512], 16, 0, 0);
    }
    __syncthreads();
#pragma unroll
    for (int ks = 0; ks < 2; ++ks) {
      const int pu = (ks * 4 + (l >> 4)) ^ (l & 7);  // swizzled 16B-unit
      short8 ah[4], al[4], bh[2], bl[2];
#pragma unroll
      for (int mf = 0; mf < 4; ++mf) {
        int row = wr * 64 + mf * 16 + (l & 15);
        ah[mf] = *(const short8*)&Ah[row * 64 + pu * 8];
        al[mf] = *(const short8*)&Al[row * 64 + pu * 8];
      }
#pragma unroll
      for (int nf = 0; nf < 2; ++nf) {
        int col = wc * 32 + nf * 16 + (l & 15);
        bh[nf] = *(const short8*)&Bh[col * 64 + pu * 8];
        bl[nf] = *(const short8*)&Bl[col * 64 + pu * 8];
      }
#pragma unroll
      for (int mf = 0; mf < 4; ++mf)
#pragma unroll
        for (int nf = 0; nf < 2; ++nf) {
          acc[mf][nf] = __builtin_amdgcn_mfma_f32_16x16x32_bf16(ah[mf], bh[nf], acc[mf][nf], 0, 0, 0);
          acc[mf][nf] = __builtin_amdgcn_mfma_f32_16x16x32_bf16(ah[mf], bl[nf], acc[mf][nf], 0, 0, 0);
          acc[mf][nf] = __builtin_amdgcn_mfma_f32_16x16x32_bf16(al[mf], bh[nf], acc[mf][nf], 0, 0, 0);
        }
    }
  }
  // ---- epilogue: C/D layout col=lane&15, row=(lane>>4)*4+reg [m89-verified] ----
#pragma unroll
  for (int mf = 0; mf < 4; ++mf)
#pragma unroll
    for (int nf = 0; nf < 2; ++nf) {
      const int col = wc * 32 + nf * 16 + (l & 15);
      if (IS_OUT) {
        const float bia = bias[col];
#pragma unroll
        for (int r = 0; r < 4; ++r) {
          int row = rowBase + wr * 64 + mf * 16 + (l >> 4) * 4 + r;
          float vv = acc[mf][nf][r] + bia;
          outp[(size_t)row * NOUTn + col] = vv > 0.f ? vv : 0.f;
        }
      } else {
        if (col < NSLR) {
          const float bia = bias[col];
#pragma unroll
          for (int r = 0; r < 4; ++r) {
            int row = rowBase + wr * 64 + mf * 16 + (l >> 4) * 4 + r;
            float vv = acc[mf][nf][r] + bia;
            vv = vv > 0.f ? vv : 0.f;
            if (col < NSn) s_ws[b * 1024 + col * 256 + (row & 255)] = vv;
            else           lr_ws[(size_t)row * NLRn + (col - NSn)] = vv;
          }
        }
      }
    }
}

// ---------------- K3: per-row KNN select + weighted mean/max ----------------
// XCD-aware remap: all 16 seg-blocks of one b stay on one XCD (L2-resident lr).
__global__ __launch_bounds__(256) void kselect(const float* __restrict__ s_ws,
                                               const float* __restrict__ lr_ws,
                                               short* __restrict__ fmh, short* __restrict__ fml,
                                               short* __restrict__ fxh, short* __restrict__ fxl) {
  __shared__ float sT[4][256];
  __shared__ unsigned int lst[4][Kn];
  const int id = blockIdx.x;
  const int xcd = id & 7;
  const int rrx = id >> 3;
  const int b = xcd + 8 * (rrx & 15);
  const int seg = rrx >> 4;
  const int t = threadIdx.x;
  const int lane = t & 63;
  const int w = t >> 6;

  {
    const float* sb = s_ws + b * 1024;
    sT[0][t] = sb[t]; sT[1][t] = sb[256 + t];
    sT[2][t] = sb[512 + t]; sT[3][t] = sb[768 + t];
  }
  __syncthreads();

  const float C = -14.4269504088896340736f;  // -10 * log2(e)
  const float* lrbase = lr_ws + (size_t)b * (256 * NLRn) + lane;

  for (int it = 0; it < 4; ++it) {
    const int i = seg * 16 + w * 4 + it;
    const float si0 = sT[0][i], si1 = sT[1][i];
    const float si2 = sT[2][i], si3 = sT[3][i];
    unsigned int kb[4];
    float vv[4];
#pragma unroll
    for (int q = 0; q < 4; ++q) {
      int j = q * 64 + lane;
      float d0 = sT[0][j] - si0;
      float d1 = sT[1][j] - si1;
      float d2_ = sT[2][j] - si2;
      float d3 = sT[3][j] - si3;
      float dd = ((d0 * d0 + d1 * d1) + d2_ * d2_) + d3 * d3;
      kb[q] = __float_as_uint(dd);  // d2 >= 0 -> bits order-preserving
      vv[q] = exp2f(C * dd);
    }
    // exact Kth-smallest via greedy bitwise search
    unsigned int T = 0;
    for (int bit = 30; bit >= 0; --bit) {
      unsigned int cand = T | (1u << bit);
      int cnt = __popcll(__ballot(kb[0] < cand)) + __popcll(__ballot(kb[1] < cand)) +
                __popcll(__ballot(kb[2] < cand)) + __popcll(__ballot(kb[3] < cand));
      if (cnt < Kn) T = cand;
    }
    int nlt = __popcll(__ballot(kb[0] < T)) + __popcll(__ballot(kb[1] < T)) +
              __popcll(__ballot(kb[2] < T)) + __popcll(__ballot(kb[3] < T));
    int rem = Kn - nlt;  // ties in ascending-j order (stable, matches top_k)
    int base = 0, ecum = 0;
#pragma unroll
    for (int q = 0; q < 4; ++q) {
      bool lt = kb[q] < T;
      bool eq = kb[q] == T;
      unsigned long long meq = __ballot(eq);
      int eqrank = ecum + mbcnt64(meq);
      bool sel = lt || (eq && (eqrank < rem));
      unsigned long long msel = __ballot(sel);
      int pos = base + mbcnt64(msel);
      if (sel)
        lst[w][pos] = (__float_as_uint(vv[q]) & 0xFFFFFF00u) | (unsigned)(q * 64 + lane);
      base += __popcll(msel);
      ecum += __popcll(meq);
    }
    // feature-parallel accumulate: lane = feature; lr gathers are XCD-L2-hot
    float accm = 0.f, accx = 0.f;  // ft >= 0 so 0-init max exact
#pragma unroll 8
    for (int tt = 0; tt < Kn; ++tt) {
      unsigned int p = lst[w][tt];
      int j = p & 0xFF;
      float v = __uint_as_float(p & 0xFFFFFF00u);
      float tv = v * lrbase[j * NLRn];
      accm += tv;
      accx = fmaxf(accx, tv);
    }
    accm *= (1.f / 40.f);
    size_t ro = ((size_t)(b * 256 + i)) * 64 + lane;
    unsigned short mh = rneb(accm);
    unsigned short ml = rneb(accm - bf2f(mh));
    unsigned short xh = rneb(accx);
    unsigned short xl = rneb(accx - bf2f(xh));
    fmh[ro] = (short)mh; fml[ro] = (short)ml;
    fxh[ro] = (short)xh; fxl[ro] = (short)xl;
  }
}

extern "C" void kernel_launch(void* const* d_in, const int* in_sizes, int n_in,
                              void* d_out, int out_size, void* d_ws, size_t ws_size,
                              hipStream_t stream) {
  const float* x = (const float*)d_in[0];
  const float* W_slr = (const float*)d_in[1];
  const float* b_slr = (const float*)d_in[2];
  const float* W_out = (const float*)d_in[3];
  const float* b_out = (const float*)d_in[4];
  float* out = (float*)d_out;

  char* p = (char*)d_ws;
  auto take = [&](size_t bytes) { char* c = p; p += (bytes + 255) & ~(size_t)255; return c; };
  short* xhi = (short*)take((size_t)ROWS * 64 * 2);
  short* xlo = (short*)take((size_t)ROWS * 64 * 2);
  short* xmhi = (short*)take(Bn * 64 * 2);
  short* xmlo = (short*)take(Bn * 64 * 2);
  short* wt1h = (short*)take(128 * 128 * 2);
  short* wt1l = (short*)take(128 * 128 * 2);
  short* wt2h = (short*)take(128 * 256 * 2);
  short* wt2l = (short*)take(128 * 256 * 2);
  float* s_ws = (float*)take(Bn * 1024 * 4);
  float* lr_ws = (float*)take((size_t)ROWS * 64 * 4);
  short* fmh = (short*)take((size_t)ROWS * 64 * 2);
  short* fml = (short*)take((size_t)ROWS * 64 * 2);
  short* fxh = (short*)take((size_t)ROWS * 64 * 2);
  short* fxl = (short*)take((size_t)ROWS * 64 * 2);

  kprep_w<<<192, 256, 0, stream>>>(W_slr, W_out, wt1h, wt1l, wt2h, wt2l);
  kprep_x<<<Bn, 256, 0, stream>>>(x, xhi, xlo, xmhi, xmlo);
  kgemm_mfma<2, false><<<ROWS / 128, 512, 0, stream>>>(
      xhi, xlo, xmhi, xmlo, nullptr, nullptr, nullptr, nullptr,
      wt1h, wt1l, b_slr, s_ws, lr_ws, nullptr);
  kselect<<<Bn * 16, 256, 0, stream>>>(s_ws, lr_ws, fmh, fml, fxh, fxl);
  kgemm_mfma<4, true><<<ROWS / 128, 512, 0, stream>>>(
      xhi, xlo, xmhi, xmlo, fmh, fml, fxh, fxl,
      wt2h, wt2l, b_out, nullptr, nullptr, out);
}

// Round 5
// 133.561 us; speedup vs baseline: 1.5597x; 1.0336x over previous
//
#include <hip/hip_runtime.h>

constexpr int Bn = 128, Vn = 256, Fn = 64;
constexpr int NSLR = 68, NSn = 4, NLRn = 64;
constexpr int Kn = 40, NOUTn = 128;
constexpr int ROWS = Bn * Vn;  // 32768
constexpr int KB2 = 192;       // GEMM2 K (x 64 | ftm 64 | ftx 64)

typedef __attribute__((ext_vector_type(8))) short short8;
typedef __attribute__((ext_vector_type(4))) float f32x4;

__device__ __forceinline__ int mbcnt64(unsigned long long m) {
  return __builtin_amdgcn_mbcnt_hi((unsigned)(m >> 32),
         __builtin_amdgcn_mbcnt_lo((unsigned)(m & 0xFFFFFFFFull), 0));
}
__device__ __forceinline__ unsigned short rneb(float v) {  // fp32 -> bf16 RNE
  unsigned u = __float_as_uint(v);
  unsigned r = u + 0x7FFFu + ((u >> 16) & 1u);
  return (unsigned short)(r >> 16);
}
__device__ __forceinline__ float bf2f(unsigned short h) {
  return __uint_as_float(((unsigned)h) << 16);
}
#define GL_LDS(gp, lp) __builtin_amdgcn_global_load_lds( \
    (const __attribute__((address_space(1))) void*)(gp), \
    (__attribute__((address_space(3))) void*)(lp), 16, 0, 0)

// ---- P0: W -> [col][k] bf16. wt1 hi/lo (x part only, k=64); wt2 single (k=192) ----
__global__ __launch_bounds__(256) void kprep_w(const float* __restrict__ W_slr,
                                               const float* __restrict__ W_out,
                                               short* __restrict__ wt1h, short* __restrict__ wt1l,
                                               short* __restrict__ wt2) {
  const int col = blockIdx.x;   // 0..127
  const int t = threadIdx.x;
  if (t < 64) {
    float val = (col < NSLR) ? W_slr[t * NSLR + col] : 0.f;
    unsigned short h = rneb(val);
    wt1h[col * 64 + t] = (short)h;
    wt1l[col * 64 + t] = (short)rneb(val - bf2f(h));
  } else {
    int k = t - 64;                         // 0..191
    int row = (k < 64) ? k : 64 + k;        // skip xmean rows 64..127
    wt2[col * KB2 + k] = (short)rneb(W_out[row * NOUTn + col]);
  }
}

// ---- P1: x -> bf16 hi/lo [row][64] + xmean fp32 [b][64] ----
__global__ __launch_bounds__(256) void kprep_x(const float* __restrict__ x,
                                               short* __restrict__ xhi, short* __restrict__ xlo,
                                               float* __restrict__ xmean) {
  const int b = blockIdx.x, t = threadIdx.x;
  const int f4 = t & 15, vg = t >> 4;
  const float4* xb = (const float4*)(x + (size_t)b * 16384);
  float4 sum = make_float4(0.f, 0.f, 0.f, 0.f);
  for (int i = 0; i < 16; ++i) {
    int v = vg * 16 + i;
    float4 val = xb[v * 16 + f4];
    sum.x += val.x; sum.y += val.y; sum.z += val.z; sum.w += val.w;
    unsigned short h0 = rneb(val.x), h1 = rneb(val.y), h2 = rneb(val.z), h3 = rneb(val.w);
    short4 hi = {(short)h0, (short)h1, (short)h2, (short)h3};
    short4 lo = {(short)rneb(val.x - bf2f(h0)), (short)rneb(val.y - bf2f(h1)),
                 (short)rneb(val.z - bf2f(h2)), (short)rneb(val.w - bf2f(h3))};
    size_t o = (size_t)b * 4096 + v * 16 + f4;
    ((short4*)xhi)[o] = hi;
    ((short4*)xlo)[o] = lo;
  }
  __shared__ float4 ps[16][16];
  ps[vg][f4] = sum;
  __syncthreads();
  if (t < 16) {
    float4 m = ps[0][t];
    for (int g = 1; g < 16; ++g) {
      float4 v = ps[g][t];
      m.x += v.x; m.y += v.y; m.z += v.z; m.w += v.w;
    }
    m.x *= (1.f / 256.f); m.y *= (1.f / 256.f); m.z *= (1.f / 256.f); m.w *= (1.f / 256.f);
    ((float4*)xmean)[b * 16 + t] = m;
  }
}

// ---- P2: fold xmean into per-b bias vectors (pure fp32) ----
__global__ __launch_bounds__(256) void kbias(const float* __restrict__ xmean,
                                             const float* __restrict__ W_slr,
                                             const float* __restrict__ b_slr,
                                             const float* __restrict__ W_out,
                                             const float* __restrict__ b_out,
                                             float* __restrict__ bias1,
                                             float* __restrict__ bias2) {
  const int b = blockIdx.x, t = threadIdx.x;
  __shared__ float xm[64];
  if (t < 64) xm[t] = xmean[b * 64 + t];
  __syncthreads();
  if (t < 128) {                       // bias2 col t
    float acc = b_out[t];
    for (int f = 0; f < 64; ++f) acc = fmaf(xm[f], W_out[(64 + f) * NOUTn + t], acc);
    bias2[b * 128 + t] = acc;
  } else {                             // bias1 col t-128
    int c = t - 128;
    float acc = 0.f;
    if (c < NSLR) {
      acc = b_slr[c];
      for (int f = 0; f < 64; ++f) acc = fmaf(xm[f], W_slr[(64 + f) * NSLR + c], acc);
    }
    bias1[b * 128 + c] = acc;
  }
}

// ---- GEMM1: 3-pass hi/lo bf16, K=64, tile 64x128, 4 waves ----
__global__ __launch_bounds__(256) void kgemm1(
    const short* __restrict__ xhi, const short* __restrict__ xlo,
    const short* __restrict__ wt1h, const short* __restrict__ wt1l,
    const float* __restrict__ bias1,
    float* __restrict__ s_ws, float* __restrict__ lr_ws) {
  __shared__ __align__(16) short Ah[4096], Al[4096], Bh[8192], Bl[8192];
  const int t = threadIdx.x, l = t & 63, w = t >> 6;
  const int wr = w >> 1, wc = w & 1;
  const int rowBase = blockIdx.x * 64;
  const int b = rowBase >> 8;
  const int lr8 = l >> 3, ul = (l & 7) ^ lr8;

#pragma unroll
  for (int rep = 0; rep < 2; ++rep) {
    const int seg = w + rep * 4;       // 0..7
    size_t o = (size_t)(rowBase + seg * 8 + lr8) * 64 + ul * 8;
    GL_LDS(xhi + o, &Ah[seg * 512]);
    GL_LDS(xlo + o, &Al[seg * 512]);
  }
#pragma unroll
  for (int rep = 0; rep < 4; ++rep) {
    const int seg = w + rep * 4;       // 0..15
    size_t o = (size_t)(seg * 8 + lr8) * 64 + ul * 8;
    GL_LDS(wt1h + o, &Bh[seg * 512]);
    GL_LDS(wt1l + o, &Bl[seg * 512]);
  }
  __syncthreads();

  f32x4 acc[2][4];
#pragma unroll
  for (int mf = 0; mf < 2; ++mf)
#pragma unroll
    for (int nf = 0; nf < 4; ++nf) acc[mf][nf] = (f32x4)(0.f);

#pragma unroll
  for (int ks = 0; ks < 2; ++ks) {
    short8 ah[2], al[2], bh[4], bl[4];
#pragma unroll
    for (int mf = 0; mf < 2; ++mf) {
      int row = wr * 32 + mf * 16 + (l & 15);
      int pu = (ks * 4 + (l >> 4)) ^ (row & 7);
      ah[mf] = *(const short8*)&Ah[row * 64 + pu * 8];
      al[mf] = *(const short8*)&Al[row * 64 + pu * 8];
    }
#pragma unroll
    for (int nf = 0; nf < 4; ++nf) {
      int col = wc * 64 + nf * 16 + (l & 15);
      int pu = (ks * 4 + (l >> 4)) ^ (col & 7);
      bh[nf] = *(const short8*)&Bh[col * 64 + pu * 8];
      bl[nf] = *(const short8*)&Bl[col * 64 + pu * 8];
    }
#pragma unroll
    for (int mf = 0; mf < 2; ++mf)
#pragma unroll
      for (int nf = 0; nf < 4; ++nf) {
        acc[mf][nf] = __builtin_amdgcn_mfma_f32_16x16x32_bf16(ah[mf], bh[nf], acc[mf][nf], 0, 0, 0);
        acc[mf][nf] = __builtin_amdgcn_mfma_f32_16x16x32_bf16(ah[mf], bl[nf], acc[mf][nf], 0, 0, 0);
        acc[mf][nf] = __builtin_amdgcn_mfma_f32_16x16x32_bf16(al[mf], bh[nf], acc[mf][nf], 0, 0, 0);
      }
  }
  // epilogue: C/D col=lane&15, row=(lane>>4)*4+reg
#pragma unroll
  for (int mf = 0; mf < 2; ++mf)
#pragma unroll
    for (int nf = 0; nf < 4; ++nf) {
      const int col = wc * 64 + nf * 16 + (l & 15);
      if (col < NSLR) {
        const float bia = bias1[b * 128 + col];
#pragma unroll
        for (int r = 0; r < 4; ++r) {
          int row = rowBase + wr * 32 + mf * 16 + (l >> 4) * 4 + r;
          float vv = acc[mf][nf][r] + bia;
          vv = vv > 0.f ? vv : 0.f;
          if (col < NSn) s_ws[b * 1024 + col * 256 + (row & 255)] = vv;
          else           lr_ws[(size_t)row * NLRn + (col - NSn)] = vv;
        }
      }
    }
}

// ---- GEMM2: single-pass bf16, K=192 (x|ftm|ftx), tile 64x128, 4 waves ----
__global__ __launch_bounds__(256) void kgemm2(
    const short* __restrict__ xhi, const short* __restrict__ fm,
    const short* __restrict__ fx, const short* __restrict__ wt2,
    const float* __restrict__ bias2, float* __restrict__ outp) {
  __shared__ __align__(16) short As[4096], Bs[8192];
  const int t = threadIdx.x, l = t & 63, w = t >> 6;
  const int wr = w >> 1, wc = w & 1;
  const int rowBase = blockIdx.x * 64;
  const int b = rowBase >> 8;
  const int lr8 = l >> 3, ul = (l & 7) ^ lr8;

  f32x4 acc[2][4];
#pragma unroll
  for (int mf = 0; mf < 2; ++mf)
#pragma unroll
    for (int nf = 0; nf < 4; ++nf) acc[mf][nf] = (f32x4)(0.f);

#pragma unroll
  for (int kc = 0; kc < 3; ++kc) {
    __syncthreads();
    const short* asrc = (kc == 0) ? xhi : (kc == 1) ? fm : fx;
#pragma unroll
    for (int rep = 0; rep < 2; ++rep) {
      const int seg = w + rep * 4;
      size_t o = (size_t)(rowBase + seg * 8 + lr8) * 64 + ul * 8;
      GL_LDS(asrc + o, &As[seg * 512]);
    }
#pragma unroll
    for (int rep = 0; rep < 4; ++rep) {
      const int seg = w + rep * 4;
      size_t o = (size_t)(seg * 8 + lr8) * KB2 + kc * 64 + ul * 8;
      GL_LDS(wt2 + o, &Bs[seg * 512]);
    }
    __syncthreads();
#pragma unroll
    for (int ks = 0; ks < 2; ++ks) {
      short8 a[2], bb[4];
#pragma unroll
      for (int mf = 0; mf < 2; ++mf) {
        int row = wr * 32 + mf * 16 + (l & 15);
        int pu = (ks * 4 + (l >> 4)) ^ (row & 7);
        a[mf] = *(const short8*)&As[row * 64 + pu * 8];
      }
#pragma unroll
      for (int nf = 0; nf < 4; ++nf) {
        int col = wc * 64 + nf * 16 + (l & 15);
        int pu = (ks * 4 + (l >> 4)) ^ (col & 7);
        bb[nf] = *(const short8*)&Bs[col * 64 + pu * 8];
      }
#pragma unroll
      for (int mf = 0; mf < 2; ++mf)
#pragma unroll
        for (int nf = 0; nf < 4; ++nf)
          acc[mf][nf] = __builtin_amdgcn_mfma_f32_16x16x32_bf16(a[mf], bb[nf], acc[mf][nf], 0, 0, 0);
    }
  }
#pragma unroll
  for (int mf = 0; mf < 2; ++mf)
#pragma unroll
    for (int nf = 0; nf < 4; ++nf) {
      const int col = wc * 64 + nf * 16 + (l & 15);
      const float bia = bias2[b * 128 + col];
#pragma unroll
      for (int r = 0; r < 4; ++r) {
        int row = rowBase + wr * 32 + mf * 16 + (l >> 4) * 4 + r;
        float vv = acc[mf][nf][r] + bia;
        outp[(size_t)row * NOUTn + col] = vv > 0.f ? vv : 0.f;
      }
    }
}

// ---- K3: per-row KNN select + weighted mean/max (exact stable top-k) ----
__global__ __launch_bounds__(256) void kselect(const float* __restrict__ s_ws,
                                               const float* __restrict__ lr_ws,
                                               short* __restrict__ fm,
                                               short* __restrict__ fx) {
  __shared__ float sT[4][256];
  __shared__ unsigned int lst[4][Kn];
  const int id = blockIdx.x;
  const int xcd = id & 7;
  const int rrx = id >> 3;
  const int b = xcd + 8 * (rrx & 15);   // all 16 seg-blocks of b on one XCD
  const int seg = rrx >> 4;
  const int t = threadIdx.x, lane = t & 63, w = t >> 6;

  {
    const float* sb = s_ws + b * 1024;
    sT[0][t] = sb[t]; sT[1][t] = sb[256 + t];
    sT[2][t] = sb[512 + t]; sT[3][t] = sb[768 + t];
  }
  __syncthreads();

  const float C = -14.4269504088896340736f;  // -10 * log2(e)
  const float* lrbase = lr_ws + (size_t)b * (256 * NLRn) + lane;

  for (int it = 0; it < 4; ++it) {
    const int i = seg * 16 + w * 4 + it;
    const float si0 = sT[0][i], si1 = sT[1][i];
    const float si2 = sT[2][i], si3 = sT[3][i];
    unsigned int kb[4];
    float vv[4];
#pragma unroll
    for (int q = 0; q < 4; ++q) {
      int j = q * 64 + lane;
      float d0 = sT[0][j] - si0;
      float d1 = sT[1][j] - si1;
      float d2_ = sT[2][j] - si2;
      float d3 = sT[3][j] - si3;
      float dd = ((d0 * d0 + d1 * d1) + d2_ * d2_) + d3 * d3;
      kb[q] = __float_as_uint(dd);  // d2 >= 0 -> order-preserving bits
      vv[q] = exp2f(C * dd);
    }
    unsigned int T = 0;
    for (int bit = 30; bit >= 0; --bit) {
      unsigned int cand = T | (1u << bit);
      int cnt = __popcll(__ballot(kb[0] < cand)) + __popcll(__ballot(kb[1] < cand)) +
                __popcll(__ballot(kb[2] < cand)) + __popcll(__ballot(kb[3] < cand));
      if (cnt < Kn) T = cand;
    }
    int nlt = __popcll(__ballot(kb[0] < T)) + __popcll(__ballot(kb[1] < T)) +
              __popcll(__ballot(kb[2] < T)) + __popcll(__ballot(kb[3] < T));
    int rem = Kn - nlt;  // ties in ascending-j order (stable, matches top_k)
    int base = 0, ecum = 0;
#pragma unroll
    for (int q = 0; q < 4; ++q) {
      bool lt = kb[q] < T;
      bool eq = kb[q] == T;
      unsigned long long meq = __ballot(eq);
      int eqrank = ecum + mbcnt64(meq);
      bool sel = lt || (eq && (eqrank < rem));
      unsigned long long msel = __ballot(sel);
      int pos = base + mbcnt64(msel);
      if (sel)
        lst[w][pos] = (__float_as_uint(vv[q]) & 0xFFFFFF00u) | (unsigned)(q * 64 + lane);
      base += __popcll(msel);
      ecum += __popcll(meq);
    }
    float accm = 0.f, accx = 0.f;  // ft >= 0 so 0-init max exact
#pragma unroll 8
    for (int tt = 0; tt < Kn; ++tt) {
      unsigned int p = lst[w][tt];
      int j = p & 0xFF;
      float v = __uint_as_float(p & 0xFFFFFF00u);
      float tv = v * lrbase[j * NLRn];
      accm += tv;
      accx = fmaxf(accx, tv);
    }
    size_t ro = ((size_t)(b * 256 + i)) * 64 + lane;
    fm[ro] = (short)rneb(accm * (1.f / 40.f));
    fx[ro] = (short)rneb(accx);
  }
}

extern "C" void kernel_launch(void* const* d_in, const int* in_sizes, int n_in,
                              void* d_out, int out_size, void* d_ws, size_t ws_size,
                              hipStream_t stream) {
  const float* x = (const float*)d_in[0];
  const float* W_slr = (const float*)d_in[1];
  const float* b_slr = (const float*)d_in[2];
  const float* W_out = (const float*)d_in[3];
  const float* b_out = (const float*)d_in[4];
  float* out = (float*)d_out;

  char* p = (char*)d_ws;
  auto take = [&](size_t bytes) { char* c = p; p += (bytes + 255) & ~(size_t)255; return c; };
  short* xhi = (short*)take((size_t)ROWS * 64 * 2);
  short* xlo = (short*)take((size_t)ROWS * 64 * 2);
  float* xmean = (float*)take(Bn * 64 * 4);
  short* wt1h = (short*)take(128 * 64 * 2);
  short* wt1l = (short*)take(128 * 64 * 2);
  short* wt2 = (short*)take(128 * KB2 * 2);
  float* bias1 = (float*)take(Bn * 128 * 4);
  float* bias2 = (float*)take(Bn * 128 * 4);
  float* s_ws = (float*)take(Bn * 1024 * 4);
  float* lr_ws = (float*)take((size_t)ROWS * 64 * 4);
  short* fm = (short*)take((size_t)ROWS * 64 * 2);
  short* fx = (short*)take((size_t)ROWS * 64 * 2);

  kprep_w<<<128, 256, 0, stream>>>(W_slr, W_out, wt1h, wt1l, wt2);
  kprep_x<<<Bn, 256, 0, stream>>>(x, xhi, xlo, xmean);
  kbias<<<Bn, 256, 0, stream>>>(xmean, W_slr, b_slr, W_out, b_out, bias1, bias2);
  kgemm1<<<ROWS / 64, 256, 0, stream>>>(xhi, xlo, wt1h, wt1l, bias1, s_ws, lr_ws);
  kselect<<<Bn * 16, 256, 0, stream>>>(s_ws, lr_ws, fm, fx);
  kgemm2<<<ROWS / 64, 256, 0, stream>>>(xhi, fm, fx, wt2, bias2, out);
}

// Round 6
// 130.578 us; speedup vs baseline: 1.5953x; 1.0228x over previous
//
#include <hip/hip_runtime.h>

constexpr int Bn = 128, Vn = 256, Fn = 64;
constexpr int NSLR = 68, NSn = 4, NLRn = 64;
constexpr int Kn = 40, NOUTn = 128;
constexpr int ROWS = Bn * Vn;  // 32768
constexpr int KB2 = 192;       // GEMM2 K (x 64 | ftm 64 | ftx 64)

typedef __attribute__((ext_vector_type(8))) short short8;
typedef __attribute__((ext_vector_type(4))) float f32x4;

__device__ __forceinline__ int mbcnt64(unsigned long long m) {
  return __builtin_amdgcn_mbcnt_hi((unsigned)(m >> 32),
         __builtin_amdgcn_mbcnt_lo((unsigned)(m & 0xFFFFFFFFull), 0));
}
__device__ __forceinline__ unsigned short rneb(float v) {  // fp32 -> bf16 RNE
  unsigned u = __float_as_uint(v);
  unsigned r = u + 0x7FFFu + ((u >> 16) & 1u);
  return (unsigned short)(r >> 16);
}
__device__ __forceinline__ float bf2f(unsigned short h) {
  return __uint_as_float(((unsigned)h) << 16);
}
#define GL_LDS(gp, lp) __builtin_amdgcn_global_load_lds( \
    (const __attribute__((address_space(1))) void*)(gp), \
    (__attribute__((address_space(3))) void*)(lp), 16, 0, 0)

// ---- K0: all prep. blocks 0..127: x split + xmean + bias1/bias2 (per b).
//          blocks 128..255: W transpose/split. ----
__global__ __launch_bounds__(256) void kprep(
    const float* __restrict__ x,
    const float* __restrict__ W_slr, const float* __restrict__ b_slr,
    const float* __restrict__ W_out, const float* __restrict__ b_out,
    short* __restrict__ xhi, short* __restrict__ xlo,
    short* __restrict__ wt1h, short* __restrict__ wt1l, short* __restrict__ wt2,
    float* __restrict__ bias1, float* __restrict__ bias2) {
  const int blk = blockIdx.x, t = threadIdx.x;
  if (blk >= Bn) {  // ---- W prep ----
    const int col = blk - Bn;  // 0..127
    if (t < 64) {
      float val = (col < NSLR) ? W_slr[t * NSLR + col] : 0.f;
      unsigned short h = rneb(val);
      wt1h[col * 64 + t] = (short)h;
      wt1l[col * 64 + t] = (short)rneb(val - bf2f(h));
    } else {
      int k = t - 64;                   // 0..191
      int row = (k < 64) ? k : 64 + k;  // skip xmean rows 64..127
      wt2[col * KB2 + k] = (short)rneb(W_out[row * NOUTn + col]);
    }
    return;
  }
  // ---- x prep for b = blk ----
  const int b = blk;
  const int f4 = t & 15, vg = t >> 4;
  const float4* xb = (const float4*)(x + (size_t)b * 16384);
  float4 sum = make_float4(0.f, 0.f, 0.f, 0.f);
  for (int i = 0; i < 16; ++i) {
    int v = vg * 16 + i;
    float4 val = xb[v * 16 + f4];
    sum.x += val.x; sum.y += val.y; sum.z += val.z; sum.w += val.w;
    unsigned short h0 = rneb(val.x), h1 = rneb(val.y), h2 = rneb(val.z), h3 = rneb(val.w);
    short4 hi = {(short)h0, (short)h1, (short)h2, (short)h3};
    short4 lo = {(short)rneb(val.x - bf2f(h0)), (short)rneb(val.y - bf2f(h1)),
                 (short)rneb(val.z - bf2f(h2)), (short)rneb(val.w - bf2f(h3))};
    size_t o = (size_t)b * 4096 + v * 16 + f4;
    ((short4*)xhi)[o] = hi;
    ((short4*)xlo)[o] = lo;
  }
  __shared__ float4 ps[16][16];
  __shared__ float xms[64];
  ps[vg][f4] = sum;
  __syncthreads();
  if (t < 16) {
    float4 m = ps[0][t];
    for (int g = 1; g < 16; ++g) {
      float4 v = ps[g][t];
      m.x += v.x; m.y += v.y; m.z += v.z; m.w += v.w;
    }
    m.x *= (1.f / 256.f); m.y *= (1.f / 256.f); m.z *= (1.f / 256.f); m.w *= (1.f / 256.f);
    ((float4*)xms)[t] = m;
  }
  __syncthreads();
  // ---- fold xmean into per-b bias (fp32 exact) ----
  if (t < 128) {
    float acc = b_out[t];
    for (int f = 0; f < 64; ++f) acc = fmaf(xms[f], W_out[(64 + f) * NOUTn + t], acc);
    bias2[b * 128 + t] = acc;
  } else {
    int c = t - 128;
    if (c < NSLR) {
      float acc = b_slr[c];
      for (int f = 0; f < 64; ++f) acc = fmaf(xms[f], W_slr[(64 + f) * NSLR + c], acc);
      bias1[b * 128 + c] = acc;
    }
  }
}

// ---- GEMM1: K=64, tile 64x128, 4 waves. 3-pass hi/lo ONLY for the s-fragment
//      (cols 0..15, wc==0/nf==0); lr cols single-pass bf16. ----
__global__ __launch_bounds__(256) void kgemm1(
    const short* __restrict__ xhi, const short* __restrict__ xlo,
    const short* __restrict__ wt1h, const short* __restrict__ wt1l,
    const float* __restrict__ bias1,
    float* __restrict__ s_ws, float* __restrict__ lr_ws) {
  __shared__ __align__(16) short Ah[4096], Al[4096], Bh[8192], Bl[1024];
  const int t = threadIdx.x, l = t & 63, w = t >> 6;
  const int wr = w >> 1, wc = w & 1;
  const int rowBase = blockIdx.x * 64;
  const int b = rowBase >> 8;
  const int lr8 = l >> 3, ul = (l & 7) ^ lr8;

#pragma unroll
  for (int rep = 0; rep < 2; ++rep) {
    const int seg = w + rep * 4;  // 0..7
    size_t o = (size_t)(rowBase + seg * 8 + lr8) * 64 + ul * 8;
    GL_LDS(xhi + o, &Ah[seg * 512]);
    GL_LDS(xlo + o, &Al[seg * 512]);
  }
#pragma unroll
  for (int rep = 0; rep < 4; ++rep) {
    const int seg = w + rep * 4;  // 0..15
    size_t o = (size_t)(seg * 8 + lr8) * 64 + ul * 8;
    GL_LDS(wt1h + o, &Bh[seg * 512]);
  }
  if (w < 2) {  // B-lo only for cols 0..15
    size_t o = (size_t)(w * 8 + lr8) * 64 + ul * 8;
    GL_LDS(wt1l + o, &Bl[w * 512]);
  }
  __syncthreads();

  f32x4 acc[2][4];
#pragma unroll
  for (int mf = 0; mf < 2; ++mf)
#pragma unroll
    for (int nf = 0; nf < 4; ++nf) acc[mf][nf] = (f32x4)(0.f);

#pragma unroll
  for (int ks = 0; ks < 2; ++ks) {
    short8 ah[2], bh[4];
#pragma unroll
    for (int mf = 0; mf < 2; ++mf) {
      int row = wr * 32 + mf * 16 + (l & 15);
      int pu = (ks * 4 + (l >> 4)) ^ (row & 7);
      ah[mf] = *(const short8*)&Ah[row * 64 + pu * 8];
    }
#pragma unroll
    for (int nf = 0; nf < 4; ++nf) {
      int col = wc * 64 + nf * 16 + (l & 15);
      int pu = (ks * 4 + (l >> 4)) ^ (col & 7);
      bh[nf] = *(const short8*)&Bh[col * 64 + pu * 8];
    }
#pragma unroll
    for (int mf = 0; mf < 2; ++mf)
#pragma unroll
      for (int nf = 0; nf < 4; ++nf)
        acc[mf][nf] = __builtin_amdgcn_mfma_f32_16x16x32_bf16(ah[mf], bh[nf], acc[mf][nf], 0, 0, 0);
    if (wc == 0) {  // precision correction passes for s-cols fragment
      int col0 = l & 15;
      int puc = (ks * 4 + (l >> 4)) ^ (col0 & 7);
      short8 bl0 = *(const short8*)&Bl[col0 * 64 + puc * 8];
#pragma unroll
      for (int mf = 0; mf < 2; ++mf) {
        int row = wr * 32 + mf * 16 + (l & 15);
        int pu = (ks * 4 + (l >> 4)) ^ (row & 7);
        short8 al = *(const short8*)&Al[row * 64 + pu * 8];
        acc[mf][0] = __builtin_amdgcn_mfma_f32_16x16x32_bf16(ah[mf], bl0, acc[mf][0], 0, 0, 0);
        acc[mf][0] = __builtin_amdgcn_mfma_f32_16x16x32_bf16(al, bh[0], acc[mf][0], 0, 0, 0);
      }
    }
  }
  // epilogue: C/D col=lane&15, row=(lane>>4)*4+reg
#pragma unroll
  for (int mf = 0; mf < 2; ++mf)
#pragma unroll
    for (int nf = 0; nf < 4; ++nf) {
      const int col = wc * 64 + nf * 16 + (l & 15);
      if (col < NSLR) {
        const float bia = bias1[b * 128 + col];
#pragma unroll
        for (int r = 0; r < 4; ++r) {
          int row = rowBase + wr * 32 + mf * 16 + (l >> 4) * 4 + r;
          float vv = acc[mf][nf][r] + bia;
          vv = vv > 0.f ? vv : 0.f;
          if (col < NSn) s_ws[b * 1024 + col * 256 + (row & 255)] = vv;
          else           lr_ws[(size_t)row * NLRn + (col - NSn)] = vv;
        }
      }
    }
}

// ---- GEMM2: single-pass bf16, K=192 (x|ftm|ftx), tile 64x128, 4 waves ----
__global__ __launch_bounds__(256) void kgemm2(
    const short* __restrict__ xhi, const short* __restrict__ fm,
    const short* __restrict__ fx, const short* __restrict__ wt2,
    const float* __restrict__ bias2, float* __restrict__ outp) {
  __shared__ __align__(16) short As[4096], Bs[8192];
  const int t = threadIdx.x, l = t & 63, w = t >> 6;
  const int wr = w >> 1, wc = w & 1;
  const int rowBase = blockIdx.x * 64;
  const int b = rowBase >> 8;
  const int lr8 = l >> 3, ul = (l & 7) ^ lr8;

  f32x4 acc[2][4];
#pragma unroll
  for (int mf = 0; mf < 2; ++mf)
#pragma unroll
    for (int nf = 0; nf < 4; ++nf) acc[mf][nf] = (f32x4)(0.f);

#pragma unroll
  for (int kc = 0; kc < 3; ++kc) {
    __syncthreads();
    const short* asrc = (kc == 0) ? xhi : (kc == 1) ? fm : fx;
#pragma unroll
    for (int rep = 0; rep < 2; ++rep) {
      const int seg = w + rep * 4;
      size_t o = (size_t)(rowBase + seg * 8 + lr8) * 64 + ul * 8;
      GL_LDS(asrc + o, &As[seg * 512]);
    }
#pragma unroll
    for (int rep = 0; rep < 4; ++rep) {
      const int seg = w + rep * 4;
      size_t o = (size_t)(seg * 8 + lr8) * KB2 + kc * 64 + ul * 8;
      GL_LDS(wt2 + o, &Bs[seg * 512]);
    }
    __syncthreads();
#pragma unroll
    for (int ks = 0; ks < 2; ++ks) {
      short8 a[2], bb[4];
#pragma unroll
      for (int mf = 0; mf < 2; ++mf) {
        int row = wr * 32 + mf * 16 + (l & 15);
        int pu = (ks * 4 + (l >> 4)) ^ (row & 7);
        a[mf] = *(const short8*)&As[row * 64 + pu * 8];
      }
#pragma unroll
      for (int nf = 0; nf < 4; ++nf) {
        int col = wc * 64 + nf * 16 + (l & 15);
        int pu = (ks * 4 + (l >> 4)) ^ (col & 7);
        bb[nf] = *(const short8*)&Bs[col * 64 + pu * 8];
      }
#pragma unroll
      for (int mf = 0; mf < 2; ++mf)
#pragma unroll
        for (int nf = 0; nf < 4; ++nf)
          acc[mf][nf] = __builtin_amdgcn_mfma_f32_16x16x32_bf16(a[mf], bb[nf], acc[mf][nf], 0, 0, 0);
    }
  }
#pragma unroll
  for (int mf = 0; mf < 2; ++mf)
#pragma unroll
    for (int nf = 0; nf < 4; ++nf) {
      const int col = wc * 64 + nf * 16 + (l & 15);
      const float bia = bias2[b * 128 + col];
#pragma unroll
      for (int r = 0; r < 4; ++r) {
        int row = rowBase + wr * 32 + mf * 16 + (l >> 4) * 4 + r;
        float vv = acc[mf][nf][r] + bia;
        outp[(size_t)row * NOUTn + col] = vv > 0.f ? vv : 0.f;
      }
    }
}

// ---- K3: per-row KNN select, 4 rows per wave BATCHED through all phases ----
__device__ __forceinline__ int cntlt(const unsigned* kbr, unsigned c) {
  return __popcll(__ballot(kbr[0] < c)) + __popcll(__ballot(kbr[1] < c)) +
         __popcll(__ballot(kbr[2] < c)) + __popcll(__ballot(kbr[3] < c));
}

__global__ __launch_bounds__(256) void kselect(const float* __restrict__ s_ws,
                                               const float* __restrict__ lr_ws,
                                               short* __restrict__ fm,
                                               short* __restrict__ fx) {
  __shared__ float sT[4][256];
  __shared__ unsigned int lst[4][4][Kn];
  const int id = blockIdx.x;
  const int xcd = id & 7;
  const int rrx = id >> 3;
  const int b = xcd + 8 * (rrx & 15);   // all 16 seg-blocks of b on one XCD
  const int seg = rrx >> 4;
  const int t = threadIdx.x, lane = t & 63, w = t >> 6;

  {
    const float* sb = s_ws + b * 1024;
    sT[0][t] = sb[t]; sT[1][t] = sb[256 + t];
    sT[2][t] = sb[512 + t]; sT[3][t] = sb[768 + t];
  }
  __syncthreads();

  // hoist candidate s-vectors (invariant over rows)
  float sj[4][4];
#pragma unroll
  for (int q = 0; q < 4; ++q)
#pragma unroll
    for (int c = 0; c < 4; ++c) sj[q][c] = sT[c][q * 64 + lane];

  const float C = -14.4269504088896340736f;  // -10 * log2(e)
  unsigned kb[4][4];
  float vv[4][4];
#pragma unroll
  for (int r = 0; r < 4; ++r) {
    const int i = seg * 16 + w * 4 + r;
    const float si0 = sT[0][i], si1 = sT[1][i], si2 = sT[2][i], si3 = sT[3][i];
#pragma unroll
    for (int q = 0; q < 4; ++q) {
      float d0 = sj[q][0] - si0;
      float d1 = sj[q][1] - si1;
      float d2_ = sj[q][2] - si2;
      float d3 = sj[q][3] - si3;
      float dd = ((d0 * d0 + d1 * d1) + d2_ * d2_) + d3 * d3;
      kb[r][q] = __float_as_uint(dd);  // d2 >= 0 -> order-preserving bits
      vv[r][q] = exp2f(C * dd);
    }
  }
  // 4-row-batched exact Kth-smallest bit search (serial chains interleaved)
  unsigned T[4] = {0u, 0u, 0u, 0u};
#pragma unroll 1
  for (int bit = 30; bit >= 0; --bit) {
    const unsigned m = 1u << bit;
    unsigned c0 = T[0] | m, c1 = T[1] | m, c2 = T[2] | m, c3 = T[3] | m;
    int n0 = cntlt(kb[0], c0);
    int n1 = cntlt(kb[1], c1);
    int n2 = cntlt(kb[2], c2);
    int n3 = cntlt(kb[3], c3);
    T[0] = (n0 < Kn) ? c0 : T[0];
    T[1] = (n1 < Kn) ? c1 : T[1];
    T[2] = (n2 < Kn) ? c2 : T[2];
    T[3] = (n3 < Kn) ? c3 : T[3];
  }
  // selection scatter (ties in ascending-j order -> matches stable top_k)
#pragma unroll
  for (int r = 0; r < 4; ++r) {
    const unsigned Tr = T[r];
    int nlt = cntlt(kb[r], Tr);
    int rem = Kn - nlt;
    int base = 0, ecum = 0;
#pragma unroll
    for (int q = 0; q < 4; ++q) {
      bool lt = kb[r][q] < Tr;
      bool eq = kb[r][q] == Tr;
      unsigned long long meq = __ballot(eq);
      int eqrank = ecum + mbcnt64(meq);
      bool sel = lt || (eq && (eqrank < rem));
      unsigned long long msel = __ballot(sel);
      int pos = base + mbcnt64(msel);
      if (sel)
        lst[w][r][pos] = (__float_as_uint(vv[r][q]) & 0xFFFFFF00u) | (unsigned)(q * 64 + lane);
      base += __popcll(msel);
      ecum += __popcll(meq);
    }
  }
  // 4-row-batched gather-accumulate: lane = feature, 16 loads in flight
  float accm[4] = {0.f, 0.f, 0.f, 0.f};
  float accx[4] = {0.f, 0.f, 0.f, 0.f};  // ft >= 0 so 0-init max exact
  const float* lrb = lr_ws + (size_t)b * (256 * NLRn) + lane;
#pragma unroll 4
  for (int tt = 0; tt < Kn; ++tt) {
#pragma unroll
    for (int r = 0; r < 4; ++r) {
      unsigned p = lst[w][r][tt];
      int j = p & 0xFF;
      float v = __uint_as_float(p & 0xFFFFFF00u);
      float tv = v * lrb[j * NLRn];
      accm[r] += tv;
      accx[r] = fmaxf(accx[r], tv);
    }
  }
#pragma unroll
  for (int r = 0; r < 4; ++r) {
    const int i = seg * 16 + w * 4 + r;
    size_t ro = ((size_t)(b * 256 + i)) * 64 + lane;
    fm[ro] = (short)rneb(accm[r] * (1.f / 40.f));
    fx[ro] = (short)rneb(accx[r]);
  }
}

extern "C" void kernel_launch(void* const* d_in, const int* in_sizes, int n_in,
                              void* d_out, int out_size, void* d_ws, size_t ws_size,
                              hipStream_t stream) {
  const float* x = (const float*)d_in[0];
  const float* W_slr = (const float*)d_in[1];
  const float* b_slr = (const float*)d_in[2];
  const float* W_out = (const float*)d_in[3];
  const float* b_out = (const float*)d_in[4];
  float* out = (float*)d_out;

  char* p = (char*)d_ws;
  auto take = [&](size_t bytes) { char* c = p; p += (bytes + 255) & ~(size_t)255; return c; };
  short* xhi = (short*)take((size_t)ROWS * 64 * 2);
  short* xlo = (short*)take((size_t)ROWS * 64 * 2);
  short* wt1h = (short*)take(128 * 64 * 2);
  short* wt1l = (short*)take(128 * 64 * 2);
  short* wt2 = (short*)take(128 * KB2 * 2);
  float* bias1 = (float*)take(Bn * 128 * 4);
  float* bias2 = (float*)take(Bn * 128 * 4);
  float* s_ws = (float*)take(Bn * 1024 * 4);
  float* lr_ws = (float*)take((size_t)ROWS * 64 * 4);
  short* fm = (short*)take((size_t)ROWS * 64 * 2);
  short* fx = (short*)take((size_t)ROWS * 64 * 2);

  kprep<<<256, 256, 0, stream>>>(x, W_slr, b_slr, W_out, b_out,
                                 xhi, xlo, wt1h, wt1l, wt2, bias1, bias2);
  kgemm1<<<ROWS / 64, 256, 0, stream>>>(xhi, xlo, wt1h, wt1l, bias1, s_ws, lr_ws);
  kselect<<<Bn * 16, 256, 0, stream>>>(s_ws, lr_ws, fm, fx);
  kgemm2<<<ROWS / 64, 256, 0, stream>>>(xhi, fm, fx, wt2, bias2, out);
}